// Round 7
// baseline (2947.008 us; speedup 1.0000x reference)
//
#include <hip/hip_runtime.h>
#include <hip/hip_bf16.h>

#define NN 100000
#define C 128
#define S 6
#define EE 200000
#define ELR 50000
#define NLAYER 4
#define GN_EPS 1e-5f
#define NBKT 14
#define KCAT (NBKT*C)                // 1792
#define TOTE (2*S*EE + 2*ELR)        // 2,500,000 edges
#define MCNT (NBKT*NN)               // 1,400,000 cells
#define NSCB ((MCNT + 255)/256)
#define NBLK2 ((NN + 127)/128)
#define VMASK 131071

typedef _Float16 f16;
typedef __attribute__((ext_vector_type(4))) _Float16 f16x4;
typedef __attribute__((ext_vector_type(8))) _Float16 f16x8;
typedef __attribute__((ext_vector_type(4))) float f32x4;
typedef __attribute__((ext_vector_type(8))) unsigned short us8;
struct alignas(8) h4 { f16 v[4]; };

__global__ void k_diag(float* out, float mb) { out[0] = mb; }

// ---- weight fp32 -> fp16 repack: [layer][slot(16)][C][C]; 0-13 buckets, 14 ctr, 15 ctr2 ----
__global__ void k_wconv(const float* __restrict__ Wpre, const float* __restrict__ Wsuc,
                        const float* __restrict__ Wleft, const float* __restrict__ Wright,
                        const float* __restrict__ Wctr, const float* __restrict__ Wctr2,
                        f16* __restrict__ out) {
  int i = blockIdx.x * blockDim.x + threadIdx.x;
  if (i >= NLAYER * 16 * C * C) return;
  int within = i & (C * C - 1);
  int b = (i >> 14) & 15;
  int layer = i >> 18;
  const float* src;
  if (b < 6)        src = Wpre  + (size_t)(layer * S + b) * C * C;
  else if (b < 12)  src = Wsuc  + (size_t)(layer * S + (b - 6)) * C * C;
  else if (b == 12) src = Wleft  + (size_t)layer * C * C;
  else if (b == 13) src = Wright + (size_t)layer * C * C;
  else if (b == 14) src = Wctr   + (size_t)layer * C * C;
  else              src = Wctr2  + (size_t)layer * C * C;
  out[i] = (f16)src[within];
}

__global__ void k_f2b(const float* __restrict__ in, f16* __restrict__ out) {
  int i = blockIdx.x * blockDim.x + threadIdx.x;
  if (i >= NN * C / 4) return;
  f32x4 v = *(const f32x4*)(in + (long)i * 4);
  h4 o;
  #pragma unroll
  for (int r = 0; r < 4; r++) o.v[r] = (f16)v[r];
  *(h4*)(out + (long)i * 4) = o;
}

// ---- CSR build over (bucket,node) cells ----
__global__ void k_count(const int* __restrict__ pu, const int* __restrict__ su,
                        const int* __restrict__ lu, const int* __restrict__ ru,
                        int* __restrict__ counts) {
  int i = blockIdx.x * blockDim.x + threadIdx.x;
  if (i >= TOTE) return;
  int u, b;
  if (i < S * EE)                { u = pu[i]; b = i / EE; }
  else if (i < 2 * S * EE)       { int j = i - S * EE; u = su[j]; b = 6 + j / EE; }
  else if (i < 2 * S * EE + ELR) { u = lu[i - 2 * S * EE]; b = 12; }
  else                           { u = ru[i - 2 * S * EE - ELR]; b = 13; }
  atomicAdd(&counts[b * NN + u], 1);
}

__global__ void k_scan1(const int* __restrict__ counts, int* __restrict__ offs, int* __restrict__ bsum) {
  __shared__ int sm[256];
  int t = threadIdx.x;
  int gidx = blockIdx.x * 256 + t;
  int v = (gidx < MCNT) ? counts[gidx] : 0;
  sm[t] = v;
  __syncthreads();
  for (int off = 1; off < 256; off <<= 1) {
    int x = (t >= off) ? sm[t - off] : 0;
    __syncthreads();
    sm[t] += x;
    __syncthreads();
  }
  if (gidx < MCNT) offs[gidx] = sm[t] - v;
  if (t == 255) bsum[blockIdx.x] = sm[255];
}

__global__ void k_scan_mid(int* __restrict__ bsum) {
  __shared__ int sm[1024];
  int t = threadIdx.x;
  int vreg[6];
  int p = 0;
  #pragma unroll
  for (int j = 0; j < 6; j++) {
    int idx = t * 6 + j;
    int x = (idx < NSCB) ? bsum[idx] : 0;
    vreg[j] = x; p += x;
  }
  sm[t] = p;
  __syncthreads();
  for (int off = 1; off < 1024; off <<= 1) {
    int x = (t >= off) ? sm[t - off] : 0;
    __syncthreads();
    sm[t] += x;
    __syncthreads();
  }
  int e = sm[t] - p;
  #pragma unroll
  for (int j = 0; j < 6; j++) {
    int idx = t * 6 + j;
    if (idx < NSCB) { bsum[idx] = e; e += vreg[j]; }
  }
}

__global__ void k_scan3(int* __restrict__ offs, const int* __restrict__ bsum) {
  int gidx = blockIdx.x * 256 + threadIdx.x;
  if (gidx >= MCNT) return;
  offs[gidx] += bsum[gidx >> 8];
}

// after k_fill: offs[cell] = END offset; start = end - counts[cell]
__global__ void k_fill(const int* __restrict__ pu, const int* __restrict__ pv,
                       const int* __restrict__ su, const int* __restrict__ sv,
                       const int* __restrict__ lu, const int* __restrict__ lv,
                       const int* __restrict__ ru, const int* __restrict__ rv,
                       int* __restrict__ offs, int* __restrict__ col) {
  int i = blockIdx.x * blockDim.x + threadIdx.x;
  if (i >= TOTE) return;
  int u, v, b;
  if (i < S * EE)                { u = pu[i]; v = pv[i]; b = i / EE; }
  else if (i < 2 * S * EE)       { int j = i - S * EE; u = su[j]; v = sv[j]; b = 6 + j / EE; }
  else if (i < 2 * S * EE + ELR) { int j = i - 2 * S * EE; u = lu[j]; v = lv[j]; b = 12; }
  else                           { int j = i - 2 * S * EE - ELR; u = ru[j]; v = rv[j]; b = 13; }
  int pos = atomicAdd(&offs[b * NN + u], 1);
  col[pos] = v;
}

// ---- KA: per-cell segmented aggregation, 32 lanes/cell ----
__global__ __launch_bounds__(512) void k_agg(
    const f16* __restrict__ fbf, const int* __restrict__ offs, const int* __restrict__ counts,
    const int* __restrict__ col, f16* __restrict__ Agg, int u0, int nrows) {
  int hw = threadIdx.x >> 5, li = threadIdx.x & 31;
  int cid = blockIdx.x * 16 + hw;
  if (cid >= 14 * nrows) return;
  int ul = cid / 14;
  int b = cid - ul * 14;
  int u = u0 + ul;
  int end = offs[b * NN + u];
  int cnt = counts[b * NN + u];
  int st = end - cnt;
  int cb = li << 2;
  float a0 = 0.f, a1 = 0.f, a2 = 0.f, a3 = 0.f;
  int j = 0;
  for (; j + 1 < cnt; j += 2) {
    int v0 = col[st + j] & VMASK;
    int v1 = col[st + j + 1] & VMASK;
    f16x4 h0 = *(const f16x4*)(fbf + (long)v0 * C + cb);
    f16x4 h1 = *(const f16x4*)(fbf + (long)v1 * C + cb);
    a0 += (float)h0[0] + (float)h1[0];
    a1 += (float)h0[1] + (float)h1[1];
    a2 += (float)h0[2] + (float)h1[2];
    a3 += (float)h0[3] + (float)h1[3];
  }
  if (j < cnt) {
    int v0 = col[st + j] & VMASK;
    f16x4 h0 = *(const f16x4*)(fbf + (long)v0 * C + cb);
    a0 += (float)h0[0]; a1 += (float)h0[1]; a2 += (float)h0[2]; a3 += (float)h0[3];
  }
  h4 o; o.v[0] = (f16)a0; o.v[1] = (f16)a1; o.v[2] = (f16)a2; o.v[3] = (f16)a3;
  *(h4*)(Agg + (long)ul * KCAT + b * C + cb) = o;
}

// ---- KB2: big GEMM (K=1920) + GN1 + ReLU [+ fused ctr2 GEMM + GN2 + residual + ReLU] ----
// LDS f1 tile: f16[128][128] with 16B-granule XOR swizzle: granule ^= (row&7)
__global__ __launch_bounds__(256) void k_big2(
    const f16* __restrict__ Agg, const f16* __restrict__ cur, const f16* __restrict__ wb,
    const float* __restrict__ gnw, const float* __restrict__ gnb,
    const float* __restrict__ g2w, const float* __restrict__ g2b,
    f16* __restrict__ nxt, float* __restrict__ fout,
    int u0, int nrows, int do2, int last) {
  __shared__ f16 f1s[16384];   // 32 KB
  int t = threadIdx.x;
  int wv = t >> 6, lane = t & 63;
  int l15 = lane & 15, g = lane >> 4;
  int row0 = blockIdx.x * 128;
  const f16x8 hz = {0,0,0,0,0,0,0,0};

  f32x4 acc[2][8];
  #pragma unroll
  for (int ri = 0; ri < 2; ri++)
    #pragma unroll
    for (int ci = 0; ci < 8; ci++) acc[ri][ci] = {0.f, 0.f, 0.f, 0.f};

#define LOADB(SRC, BF)                                                          \
  {                                                                             \
    int _s = (SRC);                                                             \
    _Pragma("unroll")                                                           \
    for (int ri = 0; ri < 2; ri++) {                                            \
      int r = row0 + wv * 32 + ri * 16 + l15;                                   \
      bool ok = (r < nrows);                                                    \
      _Pragma("unroll")                                                         \
      for (int kk = 0; kk < 4; kk++) {                                          \
        if (ok)                                                                 \
          BF[ri][kk] = (_s < 14)                                                \
            ? *(const f16x8*)(Agg + (long)r * KCAT + _s * C + kk * 32 + g * 8)  \
            : *(const f16x8*)(cur + (long)(u0 + r) * C + kk * 32 + g * 8);      \
        else BF[ri][kk] = hz;                                                   \
      }                                                                         \
    }                                                                           \
  }

#define MFMAS(SRC, BF)                                                          \
  {                                                                             \
    const f16* wsrc = wb + (SRC) * C * C;                                       \
    _Pragma("unroll")                                                           \
    for (int ci = 0; ci < 8; ci++)                                              \
      _Pragma("unroll")                                                         \
      for (int kk = 0; kk < 4; kk++) {                                          \
        f16x8 A = *(const f16x8*)(wsrc + (ci * 16 + l15) * C + kk * 32 + g * 8);\
        acc[0][ci] = __builtin_amdgcn_mfma_f32_16x16x32_f16(A, BF[0][kk], acc[0][ci], 0, 0, 0); \
        acc[1][ci] = __builtin_amdgcn_mfma_f32_16x16x32_f16(A, BF[1][kk], acc[1][ci], 0, 0, 0); \
      }                                                                         \
  }

  {
    f16x8 B0[2][4], B1[2][4];
    LOADB(0, B0);
    #pragma unroll
    for (int sp = 0; sp < 7; sp++) {
      LOADB(2 * sp + 1, B1);
      MFMAS(2 * sp, B0);
      LOADB(2 * sp + 2, B0);
      MFMAS(2 * sp + 1, B1);
    }
    MFMAS(14, B0);
  }

  // GN1 + ReLU
  #pragma unroll
  for (int ri = 0; ri < 2; ri++) {
    float s = 0.f, q = 0.f;
    #pragma unroll
    for (int ci = 0; ci < 8; ci++)
      #pragma unroll
      for (int r2 = 0; r2 < 4; r2++) { float x = acc[ri][ci][r2]; s += x; q += x * x; }
    s += __shfl_xor(s, 16); s += __shfl_xor(s, 32);
    q += __shfl_xor(q, 16); q += __shfl_xor(q, 32);
    float mean = s * (1.0f / C);
    float var = q * (1.0f / C) - mean * mean;
    float inv = rsqrtf(var + GN_EPS);
    int lrow = wv * 32 + ri * 16 + l15;
    int grow = row0 + lrow;
    #pragma unroll
    for (int ci = 0; ci < 8; ci++) {
      int ocol = ci * 16 + g * 4;
      h4 o;
      #pragma unroll
      for (int r2 = 0; r2 < 4; r2++) {
        float y = (acc[ri][ci][r2] - mean) * inv * gnw[ocol + r2] + gnb[ocol + r2];
        o.v[r2] = (f16)fmaxf(y, 0.0f);
      }
      if (do2) {
        int gran = ((ci * 2 + (g >> 1)) ^ (lrow & 7));
        *(h4*)(&f1s[lrow * 128 + gran * 8 + (g & 1) * 4]) = o;
      } else if (grow < nrows + u0 - u0 + row0 ? (row0 + lrow) < nrows : false) {
        // unreachable placeholder
      }
      if (!do2 && (row0 + lrow) < nrows)
        *(h4*)(nxt + (long)(u0 + row0 + lrow) * C + ocol) = o;
    }
  }
  if (!do2) return;
  __syncthreads();

  // ---- fused ctr2: GEMM2 (A = W2 from global, B = f1 from LDS) ----
  f32x4 a2[2][8];
  #pragma unroll
  for (int ri = 0; ri < 2; ri++)
    #pragma unroll
    for (int ci = 0; ci < 8; ci++) a2[ri][ci] = {0.f, 0.f, 0.f, 0.f};

  {
    f16x8 B2[2][4];
    #pragma unroll
    for (int ri = 0; ri < 2; ri++) {
      int lrow = wv * 32 + ri * 16 + l15;
      #pragma unroll
      for (int kk = 0; kk < 4; kk++) {
        int gran = (kk * 4 + g) ^ (lrow & 7);
        B2[ri][kk] = *(const f16x8*)(&f1s[lrow * 128 + gran * 8]);
      }
    }
    const f16* w2 = wb + 15 * C * C;
    #pragma unroll
    for (int ci = 0; ci < 8; ci++)
      #pragma unroll
      for (int kk = 0; kk < 4; kk++) {
        f16x8 A = *(const f16x8*)(w2 + (ci * 16 + l15) * C + kk * 32 + g * 8);
        a2[0][ci] = __builtin_amdgcn_mfma_f32_16x16x32_f16(A, B2[0][kk], a2[0][ci], 0, 0, 0);
        a2[1][ci] = __builtin_amdgcn_mfma_f32_16x16x32_f16(A, B2[1][kk], a2[1][ci], 0, 0, 0);
      }
  }

  // GN2 + residual + ReLU
  #pragma unroll
  for (int ri = 0; ri < 2; ri++) {
    float s = 0.f, q = 0.f;
    #pragma unroll
    for (int ci = 0; ci < 8; ci++)
      #pragma unroll
      for (int r2 = 0; r2 < 4; r2++) { float x = a2[ri][ci][r2]; s += x; q += x * x; }
    s += __shfl_xor(s, 16); s += __shfl_xor(s, 32);
    q += __shfl_xor(q, 16); q += __shfl_xor(q, 32);
    float mean = s * (1.0f / C);
    float var = q * (1.0f / C) - mean * mean;
    float inv = rsqrtf(var + GN_EPS);
    int r = row0 + wv * 32 + ri * 16 + l15;
    if (r >= nrows) continue;
    long grow = u0 + r;
    #pragma unroll
    for (int ci = 0; ci < 8; ci++) {
      int ocol = ci * 16 + g * 4;
      h4 rr = *(const h4*)(cur + grow * C + ocol);
      #pragma unroll
      for (int r2 = 0; r2 < 4; r2++) {
        float z = (a2[ri][ci][r2] - mean) * inv;
        a2[ri][ci][r2] = fmaxf(z * g2w[ocol + r2] + g2b[ocol + r2] + (float)rr.v[r2], 0.0f);
      }
      if (last) {
        *(f32x4*)(fout + grow * C + ocol) = a2[ri][ci];
      } else {
        h4 ob;
        #pragma unroll
        for (int r2 = 0; r2 < 4; r2++) ob.v[r2] = (f16)a2[ri][ci][r2];
        *(h4*)(nxt + grow * C + ocol) = ob;
      }
    }
  }
#undef LOADB
#undef MFMAS
}

// ---- K3: ctr2 GEMM + GN + residual + ReLU (fallback for last layer when Agg in d_out) ----
__global__ __launch_bounds__(256) void k_ctr2(
    const f16* __restrict__ f1bf, const f16* __restrict__ w2,
    f16* __restrict__ fbf, const float* __restrict__ gw, const float* __restrict__ gb,
    float* __restrict__ fout, int last) {
  __shared__ f16 ws[128][136];
  __shared__ float gwb[2][C];
  int t = threadIdx.x;
  int wv = t >> 6, lane = t & 63;
  int l15 = lane & 15, g = lane >> 4;
  int row0 = blockIdx.x * 128;

  if (t < C) gwb[0][t] = gw[t];
  else       gwb[1][t - C] = gb[t - C];
  #pragma unroll
  for (int i = 0; i < 8; i++) {
    int q = t + 256 * i;
    int r = q >> 4, ch = q & 15;
    *(us8*)(&ws[r][ch * 8]) = *(const us8*)(w2 + r * C + ch * 8);
  }

  const f16x8 hz = {0,0,0,0,0,0,0,0};
  f16x8 Bf[2][4];
  #pragma unroll
  for (int ri = 0; ri < 2; ri++) {
    int grow = row0 + wv * 32 + ri * 16 + l15;
    #pragma unroll
    for (int kk = 0; kk < 4; kk++) {
      if (grow < NN)
        Bf[ri][kk] = *(const f16x8*)(f1bf + (long)grow * C + kk * 32 + g * 8);
      else
        Bf[ri][kk] = hz;
    }
  }
  __syncthreads();

  f32x4 acc[2][8];
  #pragma unroll
  for (int ri = 0; ri < 2; ri++)
    #pragma unroll
    for (int ci = 0; ci < 8; ci++) acc[ri][ci] = {0.f, 0.f, 0.f, 0.f};

  #pragma unroll
  for (int ci = 0; ci < 8; ci++) {
    f16x8 A[4];
    #pragma unroll
    for (int kk = 0; kk < 4; kk++)
      A[kk] = *(const f16x8*)(&ws[ci * 16 + l15][kk * 32 + g * 8]);
    #pragma unroll
    for (int ri = 0; ri < 2; ri++)
      #pragma unroll
      for (int kk = 0; kk < 4; kk++)
        acc[ri][ci] = __builtin_amdgcn_mfma_f32_16x16x32_f16(A[kk], Bf[ri][kk], acc[ri][ci], 0, 0, 0);
  }

  float sv[2], qv[2];
  #pragma unroll
  for (int ri = 0; ri < 2; ri++) {
    float s = 0.f, q = 0.f;
    #pragma unroll
    for (int ci = 0; ci < 8; ci++)
      #pragma unroll
      for (int r = 0; r < 4; r++) { float x = acc[ri][ci][r]; s += x; q += x * x; }
    s += __shfl_xor(s, 16); s += __shfl_xor(s, 32);
    q += __shfl_xor(q, 16); q += __shfl_xor(q, 32);
    sv[ri] = s; qv[ri] = q;
  }

  #pragma unroll
  for (int ri = 0; ri < 2; ri++) {
    float mean = sv[ri] * (1.0f / C);
    float var = qv[ri] * (1.0f / C) - mean * mean;
    float inv = rsqrtf(var + GN_EPS);
    int orow = row0 + wv * 32 + ri * 16 + l15;
    if (orow >= NN) continue;
    #pragma unroll
    for (int ci = 0; ci < 8; ci++) {
      int ocol = ci * 16 + g * 4;
      h4 rr = *(const h4*)(fbf + (long)orow * C + ocol);
      h4 ob;
      f32x4 o;
      #pragma unroll
      for (int r = 0; r < 4; r++) {
        float z = (acc[ri][ci][r] - mean) * inv;
        float y = z * gwb[0][ocol + r] + gwb[1][ocol + r];
        y += (float)rr.v[r];
        y = fmaxf(y, 0.0f);
        o[r] = y;
        ob.v[r] = (f16)y;
      }
      *(h4*)(fbf + (long)orow * C + ocol) = ob;
      if (last) *(f32x4*)(fout + (long)orow * C + ocol) = o;
    }
  }
}

extern "C" void kernel_launch(void* const* d_in, const int* in_sizes, int n_in,
                              void* d_out, int out_size, void* d_ws, size_t ws_size,
                              hipStream_t stream) {
  const float* feat   = (const float*)d_in[0];
  const int* pre_u    = (const int*)d_in[1];
  const int* pre_v    = (const int*)d_in[2];
  const int* suc_u    = (const int*)d_in[3];
  const int* suc_v    = (const int*)d_in[4];
  const int* left_u   = (const int*)d_in[5];
  const int* left_v   = (const int*)d_in[6];
  const int* right_u  = (const int*)d_in[7];
  const int* right_v  = (const int*)d_in[8];
  const float* W_ctr  = (const float*)d_in[9];
  const float* norm_w = (const float*)d_in[10];
  const float* norm_b = (const float*)d_in[11];
  const float* W_ctr2 = (const float*)d_in[12];
  const float* ctr2_w = (const float*)d_in[13];
  const float* ctr2_b = (const float*)d_in[14];
  const float* W_left = (const float*)d_in[15];
  const float* W_right= (const float*)d_in[16];
  const float* W_pre  = (const float*)d_in[17];
  const float* W_suc  = (const float*)d_in[18];
  float* outf = (float*)d_out;

  const size_t NEEDED = 75000000;
  if (ws_size < NEEDED) {
    k_diag<<<1, 1, 0, stream>>>(outf, (float)(ws_size >> 20));
    return;
  }

  char* p = (char*)d_ws;
  auto alloc = [&](size_t bytes) { char* r = p; p += (bytes + 255) & ~(size_t)255; return r; };
  int* col    = (int*)alloc((size_t)TOTE * 4);       // 10.0 MB
  int* counts = (int*)alloc((size_t)MCNT * 4);       // 5.6 MB
  int* offs   = (int*)alloc((size_t)MCNT * 4);       // 5.6 MB
  int* bsum   = (int*)alloc((size_t)8192 * 4);
  f16* wbuf   = (f16*)alloc((size_t)NLAYER * 16 * C * C * 2);  // 2.1 MB
  f16* fA     = (f16*)alloc((size_t)NN * C * 2);     // 25.6 MB
  f16* fB     = (f16*)alloc((size_t)NN * C * 2);     // 25.6 MB

  size_t used = (size_t)(p - (char*)d_ws);
  size_t ws_free = (ws_size > used) ? ws_size - used : 0;
  f16* Agg;
  int CH, fuseAll;
  if (ws_free >= (size_t)25000 * KCAT * 2) { Agg = (f16*)p;     CH = 25000; fuseAll = 1; }
  else                                     { Agg = (f16*)d_out; CH = 12500; fuseAll = 0; }

  hipMemsetAsync(counts, 0, (size_t)MCNT * 4, stream);
  k_wconv<<<(NLAYER * 16 * C * C + 255) / 256, 256, 0, stream>>>(W_pre, W_suc, W_left, W_right, W_ctr, W_ctr2, wbuf);
  k_f2b<<<(NN * C / 4 + 255) / 256, 256, 0, stream>>>(feat, fA);
  k_count<<<(TOTE + 255) / 256, 256, 0, stream>>>(pre_u, suc_u, left_u, right_u, counts);
  k_scan1<<<NSCB, 256, 0, stream>>>(counts, offs, bsum);
  k_scan_mid<<<1, 1024, 0, stream>>>(bsum);
  k_scan3<<<NSCB, 256, 0, stream>>>(offs, bsum);
  k_fill<<<(TOTE + 255) / 256, 256, 0, stream>>>(pre_u, pre_v, suc_u, suc_v,
                                                 left_u, left_v, right_u, right_v, offs, col);

  f16* cur = fA;
  f16* nxt = fB;
  for (int layer = 0; layer < NLAYER; layer++) {
    const f16* wl = wbuf + (size_t)layer * 16 * C * C;
    int lastL = (layer == NLAYER - 1);
    int do2 = fuseAll || !lastL;
    for (int u0 = 0; u0 < NN; u0 += CH) {
      int nr = (NN - u0 < CH) ? (NN - u0) : CH;
      int cells = 14 * nr;
      k_agg<<<(cells + 15) / 16, 512, 0, stream>>>(cur, offs, counts, col, Agg, u0, nr);
      k_big2<<<(nr + 127) / 128, 256, 0, stream>>>(Agg, cur, wl,
                                                   norm_w + (size_t)layer * C, norm_b + (size_t)layer * C,
                                                   ctr2_w + (size_t)layer * C, ctr2_b + (size_t)layer * C,
                                                   nxt, outf, u0, nr, do2, lastL);
    }
    if (!do2) {   // fallback last layer: f1 is in nxt; run unfused ctr2 (writes fout)
      k_ctr2<<<NBLK2, 256, 0, stream>>>(nxt, wl + 15 * C * C,
                                        cur, ctr2_w + (size_t)layer * C, ctr2_b + (size_t)layer * C,
                                        outf, 1);
    }
    f16* tmp = cur; cur = nxt; nxt = tmp;
  }
}